// Round 1
// baseline (313.322 us; speedup 1.0000x reference)
//
#include <hip/hip_runtime.h>
#include <cstdint>
#include <cstddef>

// Problem: quantized linear (Brevitas-style int8 per-tensor symmetric).
//   x [N=32768, K=1024] f32, w [M=1024, K=1024] f32, bias [M] f32.
//   sx = max|x|/127, sw = max|w|/127; qx = clip(rne(x/sx)), qw likewise (int8)
//   out[n,m] = (sum_k qx[n,k]*qw[m,k]) * sx*sw + bias[m]   (f32)
//
// ws layout: [0..7] two uint absmax bit-patterns; [64..] qx (N*K int8); then qw (M*K int8).

typedef int v4i __attribute__((ext_vector_type(4)));

#define QMAXF 127.0f
#define KDIM 1024
#define MDIM 1024

__global__ void init_ws(unsigned* amax) {
  amax[0] = 0u;
  amax[1] = 0u;
}

// blockIdx.y == 0 -> x, == 1 -> w. Max is order-independent => exact.
__global__ void absmax2(const float4* __restrict__ x, int nx4,
                        const float4* __restrict__ w, int nw4,
                        unsigned* __restrict__ amax) {
  const float4* p = (blockIdx.y == 0) ? x : w;
  int n4 = (blockIdx.y == 0) ? nx4 : nw4;
  float m = 0.0f;
  for (int i = blockIdx.x * blockDim.x + threadIdx.x; i < n4;
       i += gridDim.x * blockDim.x) {
    float4 v = p[i];
    m = fmaxf(m, fmaxf(fmaxf(fabsf(v.x), fabsf(v.y)),
                       fmaxf(fabsf(v.z), fabsf(v.w))));
  }
  // wave-64 reduction
  for (int off = 32; off; off >>= 1) m = fmaxf(m, __shfl_down(m, off, 64));
  __shared__ float wm[4];
  int lane = threadIdx.x & 63, wid = threadIdx.x >> 6;
  if (lane == 0) wm[wid] = m;
  __syncthreads();
  if (threadIdx.x == 0) {
    float bm = wm[0];
    for (int i = 1; i < ((int)blockDim.x >> 6); ++i) bm = fmaxf(bm, wm[i]);
    // non-negative floats: uint bit pattern is monotonic
    atomicMax(&amax[blockIdx.y], __float_as_uint(bm));
  }
}

// blockIdx.y == 0 -> quantize x -> qx ; == 1 -> w -> qw.
// Semantics match ref exactly: s = amax/127 (fp32 div), v/s (fp32 div),
// rintf = round-half-to-even (np.round), clip to [-127,127].
__global__ void quant2(const float4* __restrict__ x, int nx4,
                       const float4* __restrict__ w, int nw4,
                       const unsigned* __restrict__ amax,
                       int* __restrict__ qx, int* __restrict__ qw) {
  int sel = blockIdx.y;
  const float4* p = sel ? w : x;
  int n4 = sel ? nw4 : nx4;
  int* q = sel ? qw : qx;
  float s = __uint_as_float(amax[sel]) / QMAXF;
  for (int i = blockIdx.x * blockDim.x + threadIdx.x; i < n4;
       i += gridDim.x * blockDim.x) {
    float4 v = p[i];
    int b0 = (int)fminf(fmaxf(rintf(v.x / s), -QMAXF), QMAXF);
    int b1 = (int)fminf(fmaxf(rintf(v.y / s), -QMAXF), QMAXF);
    int b2 = (int)fminf(fmaxf(rintf(v.z / s), -QMAXF), QMAXF);
    int b3 = (int)fminf(fmaxf(rintf(v.w / s), -QMAXF), QMAXF);
    unsigned packed = ((unsigned)(b0 & 255)) | ((unsigned)(b1 & 255) << 8) |
                      ((unsigned)(b2 & 255) << 16) | ((unsigned)(b3 & 255) << 24);
    q[i] = (int)packed;
  }
}

__device__ __forceinline__ void ld_lds16(const void* g, void* l) {
  __builtin_amdgcn_global_load_lds(
      (__attribute__((address_space(1))) void*)(void*)g,
      (__attribute__((address_space(3))) void*)l, 16, 0, 0);
}

// 128x128 block tile, BK=64 (64 B/row of int8 — same byte geometry as the
// verified m97 bf16 BK=32 kernel). 4 waves in 2x2, each computes 64x64 via
// 4x4 grid of 16x16x64 i8 MFMAs.
__global__ __launch_bounds__(256) void gemm_i8(
    const char* __restrict__ qx, const char* __restrict__ qw,
    const float* __restrict__ bias, const unsigned* __restrict__ amax,
    float* __restrict__ out) {
  __shared__ __align__(16) char smA[128 * 64];
  __shared__ __align__(16) char smB[128 * 64];

  const int tid = threadIdx.x;
  const int wave = tid >> 6;
  const int lane = tid & 63;
  const int bm = blockIdx.x;  // M/128 = 8
  const int bn = blockIdx.y;  // N/128 = 256
  const int wn = wave >> 1;   // 0..1
  const int wm = wave & 1;    // 0..1

  const char* xbase = qx + (size_t)(bn * 128) * KDIM;
  const char* wbase = qw + (size_t)(bm * 128) * KDIM;

  v4i acc[4][4] = {};

  // staging: each wave stages 32 rows of A and 32 rows of B (2 calls each,
  // 16 rows/call, lane i -> row (i>>2), byte seg (i&3)*16). LDS dest is
  // wave-uniform base + lane*16 (HW rule), layout [128][64] contiguous.
  const int srow = wave * 32 + (lane >> 2);
  const int skb = (lane & 3) * 16;

  for (int kt = 0; kt < KDIM / 64; ++kt) {
    const int kb = kt * 64;
    ld_lds16(xbase + (size_t)srow * KDIM + kb + skb, smA + (wave * 32) * 64);
    ld_lds16(xbase + (size_t)(srow + 16) * KDIM + kb + skb,
             smA + (wave * 32 + 16) * 64);
    ld_lds16(wbase + (size_t)srow * KDIM + kb + skb, smB + (wave * 32) * 64);
    ld_lds16(wbase + (size_t)(srow + 16) * KDIM + kb + skb,
             smB + (wave * 32 + 16) * 64);
    __syncthreads();  // drains vmcnt then barrier -> tiles visible

    const int kq = (lane >> 4) * 16;  // k byte quarter within row
    v4i afrag[4], bfrag[4];
#pragma unroll
    for (int i = 0; i < 4; ++i)
      afrag[i] = *(const v4i*)(smA + (wn * 64 + i * 16 + (lane & 15)) * 64 + kq);
#pragma unroll
    for (int j = 0; j < 4; ++j)
      bfrag[j] = *(const v4i*)(smB + (wm * 64 + j * 16 + (lane & 15)) * 64 + kq);

#pragma unroll
    for (int i = 0; i < 4; ++i)
#pragma unroll
      for (int j = 0; j < 4; ++j)
        acc[i][j] =
            __builtin_amdgcn_mfma_i32_16x16x64_i8(afrag[i], bfrag[j], acc[i][j], 0, 0, 0);
    __syncthreads();  // all waves done reading LDS before next stage
  }

  // epilogue: C/D layout col=lane&15 (m), row=(lane>>4)*4+reg (n)
  const float s = (__uint_as_float(amax[0]) / QMAXF) *
                  (__uint_as_float(amax[1]) / QMAXF);
  const int mcol = bm * 128 + wm * 64 + (lane & 15);
  const int nbase = bn * 128 + wn * 64 + ((lane >> 4) << 2);
  float bv[4];
#pragma unroll
  for (int j = 0; j < 4; ++j) bv[j] = bias[mcol + j * 16];
#pragma unroll
  for (int i = 0; i < 4; ++i) {
#pragma unroll
    for (int r = 0; r < 4; ++r) {
      const int n = nbase + i * 16 + r;
      float* orow = out + (size_t)n * MDIM + mcol;
#pragma unroll
      for (int j = 0; j < 4; ++j)
        orow[j * 16] = (float)acc[i][j][r] * s + bv[j];
    }
  }
}

extern "C" void kernel_launch(void* const* d_in, const int* in_sizes, int n_in,
                              void* d_out, int out_size, void* d_ws, size_t ws_size,
                              hipStream_t stream) {
  const float* x = (const float*)d_in[0];
  const float* w = (const float*)d_in[1];
  const float* bias = (const float*)d_in[2];
  float* out = (float*)d_out;

  const int NX = in_sizes[0];          // N*K = 33554432
  const int NW = in_sizes[1];          // M*K = 1048576
  const int N = NX / KDIM;             // 32768

  unsigned* amax = (unsigned*)d_ws;
  char* qx = (char*)d_ws + 64;
  char* qw = qx + (size_t)NX;

  init_ws<<<1, 1, 0, stream>>>(amax);

  dim3 rgrid(1024, 2);
  absmax2<<<rgrid, 256, 0, stream>>>((const float4*)x, NX / 4,
                                     (const float4*)w, NW / 4, amax);

  quant2<<<rgrid, 256, 0, stream>>>((const float4*)x, NX / 4,
                                    (const float4*)w, NW / 4, amax,
                                    (int*)qx, (int*)qw);

  dim3 ggrid(MDIM / 128, N / 128);
  gemm_i8<<<ggrid, 256, 0, stream>>>(qx, qw, bias, amax, out);
}

// Round 2
// 298.148 us; speedup vs baseline: 1.0509x; 1.0509x over previous
//
#include <hip/hip_runtime.h>
#include <cstdint>
#include <cstddef>

// Quantized linear (Brevitas-style int8 per-tensor symmetric).
//   x [N=32768, K=1024] f32, w [M=1024, K=1024] f32, bias [M] f32.
//   sx = max|x|/127, sw = max|w|/127; qx = clip(rne(x/sx)) int8, qw likewise
//   out[n,m] = (sum_k qx[n,k]*qw[m,k]) * sx*sw + bias[m]   (f32)
//
// ws layout:
//   [0..7]      2 floats: final amax_x, amax_w  (written by quant kernel)
//   [64..]      544 float per-block partial maxes (512 for x, 32 for w)
//   [4096..]    qx (N*K int8), then qw (M*K int8)

typedef int v4i __attribute__((ext_vector_type(4)));

#define QMAXF 127.0f
#define KDIM 1024
#define MDIM 1024
#define NBX 512   // absmax blocks for x
#define NBW 32    // absmax blocks for w

// ---------------- pass 1: per-block partial |max| (no atomics, no init) ----
__global__ __launch_bounds__(256) void absmax_partial(
    const float4* __restrict__ x, int nx4,
    const float4* __restrict__ w, int nw4,
    float* __restrict__ partials) {
  const int b = blockIdx.x;
  const bool isw = (b >= NBX);
  const float4* __restrict__ p = isw ? w : x;
  const int n4 = isw ? nw4 : nx4;
  const int nb = isw ? NBW : NBX;
  const int bb = isw ? (b - NBX) : b;
  const int stride = nb * 256;

  float m0 = 0.f, m1 = 0.f, m2 = 0.f, m3 = 0.f;
  int i = bb * 256 + threadIdx.x;
  for (; i + 3 * stride < n4; i += 4 * stride) {
    float4 v0 = p[i], v1 = p[i + stride], v2 = p[i + 2 * stride],
           v3 = p[i + 3 * stride];
    m0 = fmaxf(m0, fmaxf(fmaxf(fabsf(v0.x), fabsf(v0.y)),
                         fmaxf(fabsf(v0.z), fabsf(v0.w))));
    m1 = fmaxf(m1, fmaxf(fmaxf(fabsf(v1.x), fabsf(v1.y)),
                         fmaxf(fabsf(v1.z), fabsf(v1.w))));
    m2 = fmaxf(m2, fmaxf(fmaxf(fabsf(v2.x), fabsf(v2.y)),
                         fmaxf(fabsf(v2.z), fabsf(v2.w))));
    m3 = fmaxf(m3, fmaxf(fmaxf(fabsf(v3.x), fabsf(v3.y)),
                         fmaxf(fabsf(v3.z), fabsf(v3.w))));
  }
  for (; i < n4; i += stride) {
    float4 v = p[i];
    m0 = fmaxf(m0, fmaxf(fmaxf(fabsf(v.x), fabsf(v.y)),
                         fmaxf(fabsf(v.z), fabsf(v.w))));
  }
  float m = fmaxf(fmaxf(m0, m1), fmaxf(m2, m3));
  for (int off = 32; off; off >>= 1) m = fmaxf(m, __shfl_down(m, off, 64));
  __shared__ float wm[4];
  const int lane = threadIdx.x & 63, wid = threadIdx.x >> 6;
  if (lane == 0) wm[wid] = m;
  __syncthreads();
  if (threadIdx.x == 0)
    partials[b] = fmaxf(fmaxf(wm[0], wm[1]), fmaxf(wm[2], wm[3]));
}

// ---------------- pass 2: reduce partials + quantize (16 elems/iter) -------
__global__ __launch_bounds__(256) void quant2(
    const float4* __restrict__ x, int nx16,
    const float4* __restrict__ w, int nw16,
    const float* __restrict__ partials,
    v4i* __restrict__ qx, v4i* __restrict__ qw,
    float* __restrict__ amax_out) {
  const int sel = blockIdx.y;
  // reduce this tensor's partials (identical result in every block)
  const float* pp = partials + (sel ? NBX : 0);
  const int np = sel ? NBW : NBX;
  float m = 0.f;
  for (int i = threadIdx.x; i < np; i += 256) m = fmaxf(m, pp[i]);
  for (int off = 32; off; off >>= 1) m = fmaxf(m, __shfl_down(m, off, 64));
  __shared__ float wm[4];
  __shared__ float bmax;
  const int lane = threadIdx.x & 63, wid = threadIdx.x >> 6;
  if (lane == 0) wm[wid] = m;
  __syncthreads();
  if (threadIdx.x == 0) {
    float bm = fmaxf(fmaxf(wm[0], wm[1]), fmaxf(wm[2], wm[3]));
    bmax = bm;
    if (blockIdx.x == 0) amax_out[sel] = bm;  // publish for GEMM epilogue
  }
  __syncthreads();
  const float amax = bmax;
  const float r = QMAXF / amax;

  const float4* __restrict__ p = sel ? w : x;
  const int n16 = sel ? nw16 : nx16;
  v4i* __restrict__ q = sel ? qw : qx;

  for (int i = blockIdx.x * 256 + threadIdx.x; i < n16;
       i += gridDim.x * 256) {
    float4 v0 = p[4 * i], v1 = p[4 * i + 1], v2 = p[4 * i + 2],
           v3 = p[4 * i + 3];
    v4i o;
#define QPK(V)                                                         \
  ((((int)fminf(fmaxf(rintf((V).x * r), -QMAXF), QMAXF)) & 255) |      \
   ((((int)fminf(fmaxf(rintf((V).y * r), -QMAXF), QMAXF)) & 255) << 8) | \
   ((((int)fminf(fmaxf(rintf((V).z * r), -QMAXF), QMAXF)) & 255) << 16) | \
   ((((int)fminf(fmaxf(rintf((V).w * r), -QMAXF), QMAXF)) & 255) << 24))
    o[0] = QPK(v0);
    o[1] = QPK(v1);
    o[2] = QPK(v2);
    o[3] = QPK(v3);
#undef QPK
    q[i] = o;
  }
}

// ---------------- pass 3: i8 MFMA GEMM, 128x128 tile, BK=128, swizzled -----
__device__ __forceinline__ void ld_lds16(const void* g, void* l) {
  __builtin_amdgcn_global_load_lds(
      (__attribute__((address_space(1))) void*)(void*)g,
      (__attribute__((address_space(3))) void*)l, 16, 0, 0);
}

// LDS layout: [128 rows][8 segs of 16B], physical seg = logical seg ^ (row&7).
// Swizzle applied on the *global source* side during global_load_lds (dest is
// forced wave-uniform-base + lane*16). Fragment reads then spread 16-lane
// groups evenly across all 32 banks (8 lanes per 4-bank group = b128 floor).
__global__ __launch_bounds__(256) void gemm_i8(
    const char* __restrict__ qx, const char* __restrict__ qw,
    const float* __restrict__ bias, const float* __restrict__ amax,
    float* __restrict__ out) {
  __shared__ __align__(16) char smA[128 * 128];
  __shared__ __align__(16) char smB[128 * 128];

  const int tid = threadIdx.x;
  const int wave = tid >> 6;
  const int lane = tid & 63;
  const int bm = blockIdx.x;  // M/128 = 8
  const int bn = blockIdx.y;  // N/128 = 256
  const int wn = wave >> 1;
  const int wm = wave & 1;

  const char* xb = qx + (size_t)(bn * 128) * KDIM;
  const char* wb = qw + (size_t)(bm * 128) * KDIM;

  v4i acc[4][4] = {};

  const int lrow = lane >> 3;          // 0..7 within an 8-row staging slab
  const int sgx = (lane & 7) ^ lrow;   // swizzled source segment

  for (int kt = 0; kt < 8; ++kt) {
    const int kb = kt * 128;
#pragma unroll
    for (int c = 0; c < 4; ++c) {
      const int rbase = c * 32 + wave * 8;  // 8 rows per wave-call
      ld_lds16(xb + (size_t)(rbase + lrow) * KDIM + kb + sgx * 16,
               smA + rbase * 128);
      ld_lds16(wb + (size_t)(rbase + lrow) * KDIM + kb + sgx * 16,
               smB + rbase * 128);
    }
    __syncthreads();  // vmcnt(0) drain + barrier: tiles visible

#pragma unroll
    for (int kc = 0; kc < 2; ++kc) {
      const int s = kc * 4 + (lane >> 4);  // logical 16B seg in row
      v4i a[4], b[4];
#pragma unroll
      for (int i = 0; i < 4; ++i) {
        const int r = wn * 64 + i * 16 + (lane & 15);
        a[i] = *(const v4i*)(smA + r * 128 + ((s ^ (r & 7)) * 16));
      }
#pragma unroll
      for (int j = 0; j < 4; ++j) {
        const int r = wm * 64 + j * 16 + (lane & 15);
        b[j] = *(const v4i*)(smB + r * 128 + ((s ^ (r & 7)) * 16));
      }
#pragma unroll
      for (int i = 0; i < 4; ++i)
#pragma unroll
        for (int j = 0; j < 4; ++j)
          acc[i][j] = __builtin_amdgcn_mfma_i32_16x16x64_i8(a[i], b[j],
                                                            acc[i][j], 0, 0, 0);
    }
    __syncthreads();
  }

  // epilogue: C/D layout col=lane&15 (m), row=(lane>>4)*4+reg (n)
  const float s = (amax[0] / QMAXF) * (amax[1] / QMAXF);
  const int mcol = bm * 128 + wm * 64 + (lane & 15);
  const int nbase = bn * 128 + wn * 64 + ((lane >> 4) << 2);
  float bv[4];
#pragma unroll
  for (int j = 0; j < 4; ++j) bv[j] = bias[mcol + j * 16];
#pragma unroll
  for (int i = 0; i < 4; ++i) {
#pragma unroll
    for (int r = 0; r < 4; ++r) {
      const int n = nbase + i * 16 + r;
      float* orow = out + (size_t)n * MDIM + mcol;
#pragma unroll
      for (int j = 0; j < 4; ++j)
        orow[j * 16] = (float)acc[i][j][r] * s + bv[j];
    }
  }
}

extern "C" void kernel_launch(void* const* d_in, const int* in_sizes, int n_in,
                              void* d_out, int out_size, void* d_ws, size_t ws_size,
                              hipStream_t stream) {
  const float* x = (const float*)d_in[0];
  const float* w = (const float*)d_in[1];
  const float* bias = (const float*)d_in[2];
  float* out = (float*)d_out;

  const int NX = in_sizes[0];  // N*K = 33554432
  const int NW = in_sizes[1];  // M*K = 1048576
  const int N = NX / KDIM;     // 32768

  float* amax = (float*)d_ws;
  float* partials = (float*)((char*)d_ws + 64);
  char* qx = (char*)d_ws + 4096;
  char* qw = qx + (size_t)NX;

  absmax_partial<<<NBX + NBW, 256, 0, stream>>>(
      (const float4*)x, NX / 4, (const float4*)w, NW / 4, partials);

  dim3 qgrid(1024, 2);
  quant2<<<qgrid, 256, 0, stream>>>((const float4*)x, NX / 16,
                                    (const float4*)w, NW / 16, partials,
                                    (v4i*)qx, (v4i*)qw, amax);

  dim3 ggrid(MDIM / 128, N / 128);
  gemm_i8<<<ggrid, 256, 0, stream>>>(qx, qw, bias, amax, out);
}